// Round 8
// baseline (61.103 us; speedup 1.0000x reference)
//
#include <hip/hip_runtime.h>

// TripletLoss: N=8192, D=512, T=65536
//   loss = mean_t softplus(||x_i - x_j||^2 - ||x_i - x_k||^2)
//
// Round 8: r7 gather (fp8, UNR=8, half-wave uint4 loads, launch_bounds(256,4))
// + fused final reduction: block partial -> atomicAdd into 64 spread slots
// (blockIdx&63, 64B apart), ACQ_REL done-counter, last block sums the slots
// and writes out[0]. Kernel C eliminated (2 kernels total).

typedef float floatx2 __attribute__((ext_vector_type(2)));

#define NTRIP 65536
#define DIM   512
#define NROWS 8192
#define WPB   4                    // waves per block
#define UNR   8                    // triplets per wave
#define TPB   (WPB * UNR)          // 32
#define NBLK  (NTRIP / TPB)        // 2048
#define XQ_BYTES ((size_t)NROWS * DIM)   // 4 MiB
#define NSLOT 64
#define SLOT_STRIDE 16             // floats; 64 B apart

__device__ __forceinline__ float softplus_stable(float z) {
    return fmaxf(z, 0.f) + log1pf(expf(-fabsf(z)));
}

__device__ __forceinline__ unsigned int enc4(float a, float b, float c, float d) {
    unsigned int w = __builtin_amdgcn_cvt_pk_fp8_f32(a, b, 0, false);
    w = __builtin_amdgcn_cvt_pk_fp8_f32(c, d, w, true);
    return w;
}

__device__ __forceinline__ void decode4(unsigned int w, float* f) {
    floatx2 p0 = __builtin_amdgcn_cvt_pk_f32_fp8(w, false);
    floatx2 p1 = __builtin_amdgcn_cvt_pk_f32_fp8(w, true);
    f[0] = p0.x; f[1] = p0.y; f[2] = p1.x; f[3] = p1.y;
}

__device__ __forceinline__ void decode16(uint4 v, float* f) {
    decode4(v.x, f);  decode4(v.y, f + 4);
    decode4(v.z, f + 8); decode4(v.w, f + 12);
}

// ------- Kernel A: fp32 -> fp8 (16 elems/thread); zero slots+counter -------
__global__ __launch_bounds__(256) void convert8_kernel(
    const float4* __restrict__ x, uint4* __restrict__ xq,
    float* __restrict__ slots, unsigned int* __restrict__ counter)
{
    if (blockIdx.x == 0) {
        if (threadIdx.x < NSLOT) slots[threadIdx.x * SLOT_STRIDE] = 0.f;
        if (threadIdx.x == NSLOT) *counter = 0u;
    }
    const int idx = blockIdx.x * 256 + threadIdx.x;
    float4 a = x[(size_t)idx * 4 + 0];
    float4 b = x[(size_t)idx * 4 + 1];
    float4 c = x[(size_t)idx * 4 + 2];
    float4 d = x[(size_t)idx * 4 + 3];
    uint4 o;
    o.x = enc4(a.x, a.y, a.z, a.w);
    o.y = enc4(b.x, b.y, b.z, b.w);
    o.z = enc4(c.x, c.y, c.z, c.w);
    o.w = enc4(d.x, d.y, d.z, d.w);
    xq[idx] = o;
}

// ---- Kernel B: fp8 gather + loss + fused last-block final reduction ----
__global__ __launch_bounds__(256, 4) void gather8_kernel(
    const uint4* __restrict__ xq,     // row stride = 32 uint4 (512 B)
    const int*   __restrict__ trip,
    float*       __restrict__ slots,
    unsigned int* __restrict__ counter,
    float*       __restrict__ out)
{
    const int lane = threadIdx.x & 63;
    const int half = lane >> 5;        // 0: even triplet of pair; 1: odd
    const int l5   = lane & 31;        // 16B slot within row
    const int wib  = threadIdx.x >> 6;
    const int t0   = (blockIdx.x * WPB + wib) * UNR;

    // 24 indices via 6 wave-uniform int4 loads
    const int4* tp = (const int4*)(trip + 3 * t0);
    int4 w0 = tp[0], w1 = tp[1], w2 = tp[2];
    int4 w3 = tp[3], w4 = tp[4], w5 = tp[5];
    const int id[24] = { w0.x, w0.y, w0.z, w0.w, w1.x, w1.y, w1.z, w1.w,
                         w2.x, w2.y, w2.z, w2.w, w3.x, w3.y, w3.z, w3.w,
                         w4.x, w4.y, w4.z, w4.w, w5.x, w5.y, w5.z, w5.w };

    // 12 load instructions, each fetching two rows (one per 32-lane half).
    uint4 r[4][3];
    #pragma unroll
    for (int g = 0; g < 4; ++g) {
        #pragma unroll
        for (int m = 0; m < 3; ++m) {
            const int row = half ? id[3 * (2 * g + 1) + m]
                                 : id[3 * (2 * g) + m];
            r[g][m] = xq[(size_t)row * 32 + l5];
        }
    }

    float z[4] = {0.f, 0.f, 0.f, 0.f};
    #pragma unroll
    for (int g = 0; g < 4; ++g) {
        float fa[16], fb[16], fc[16];
        decode16(r[g][0], fa);
        decode16(r[g][1], fb);
        decode16(r[g][2], fc);
        #pragma unroll
        for (int e = 0; e < 16; ++e) {
            float d = fa[e] - fb[e];
            float q = fa[e] - fc[e];
            z[g] += d * d - q * q;
        }
    }

    // reduce within each 32-lane half (xor masks 1..16 stay inside a half)
    #pragma unroll
    for (int m = 1; m <= 16; m <<= 1) {
        #pragma unroll
        for (int g = 0; g < 4; ++g)
            z[g] += __shfl_xor(z[g], m, 64);
    }

    float sp = (softplus_stable(z[0]) + softplus_stable(z[1])) +
               (softplus_stable(z[2]) + softplus_stable(z[3]));
    sp += __shfl_xor(sp, 32, 64);      // wave total over 8 triplets

    __shared__ float wsum[WPB];
    if (lane == 0) wsum[wib] = sp;
    __syncthreads();

    __shared__ bool amlast;
    if (threadIdx.x == 0) {
        float bs = (wsum[0] + wsum[1]) + (wsum[2] + wsum[3]);
        // device-scope atomic lands at L2 (coherent); spread slots avoid
        // same-address serialization (<=32 adds per slot)
        atomicAdd(&slots[(blockIdx.x & (NSLOT - 1)) * SLOT_STRIDE], bs);
        // release: slot add ordered before counter bump; acquire on read
        unsigned int prev = __hip_atomic_fetch_add(
            counter, 1u, __ATOMIC_ACQ_REL, __HIP_MEMORY_SCOPE_AGENT);
        amlast = (prev == NBLK - 1);
    }
    __syncthreads();

    if (amlast) {
        // last block: sum the 64 slots (atomic loads -> L2-coherent)
        if (threadIdx.x < NSLOT) {
            float v = __hip_atomic_load(
                &slots[threadIdx.x * SLOT_STRIDE],
                __ATOMIC_RELAXED, __HIP_MEMORY_SCOPE_AGENT);
            #pragma unroll
            for (int m = 1; m < NSLOT; m <<= 1)
                v += __shfl_xor(v, m, 64);
            if (threadIdx.x == 0)
                out[0] = v / (float)NTRIP;
        }
    }
}

// ---------------- fp32 fallback path (proven) ----------------
__global__ __launch_bounds__(256) void triplet_partial_f32(
    const float* __restrict__ x,
    const int*   __restrict__ trip,
    float*       __restrict__ partials)
{
    const int lane = threadIdx.x & 63;
    const int wib  = threadIdx.x >> 6;
    const int t    = blockIdx.x * 4 + wib;
    const int i = trip[3 * t + 0];
    const int j = trip[3 * t + 1];
    const int k = trip[3 * t + 2];
    const float4* pi = (const float4*)(x + (size_t)i * DIM) + lane * 2;
    const float4* pj = (const float4*)(x + (size_t)j * DIM) + lane * 2;
    const float4* pk = (const float4*)(x + (size_t)k * DIM) + lane * 2;
    float4 a0 = pi[0], a1 = pi[1];
    float4 b0 = pj[0], b1 = pj[1];
    float4 c0 = pk[0], c1 = pk[1];
    float z = 0.f;
    {
        float d;
        d = a0.x-b0.x; z += d*d; d = a0.y-b0.y; z += d*d;
        d = a0.z-b0.z; z += d*d; d = a0.w-b0.w; z += d*d;
        d = a1.x-b1.x; z += d*d; d = a1.y-b1.y; z += d*d;
        d = a1.z-b1.z; z += d*d; d = a1.w-b1.w; z += d*d;
        d = a0.x-c0.x; z -= d*d; d = a0.y-c0.y; z -= d*d;
        d = a0.z-c0.z; z -= d*d; d = a0.w-c0.w; z -= d*d;
        d = a1.x-c1.x; z -= d*d; d = a1.y-c1.y; z -= d*d;
        d = a1.z-c1.z; z -= d*d; d = a1.w-c1.w; z -= d*d;
    }
    #pragma unroll
    for (int m = 1; m < 64; m <<= 1) z += __shfl_xor(z, m, 64);
    __shared__ float wsum[4];
    if (lane == 0) wsum[wib] = softplus_stable(z);
    __syncthreads();
    if (threadIdx.x == 0)
        partials[blockIdx.x] = (wsum[0] + wsum[1]) + (wsum[2] + wsum[3]);
}

__global__ __launch_bounds__(1024) void reduce_kernel(
    const float* __restrict__ partials, float* __restrict__ out, int n)
{
    float s = 0.f;
    for (int idx = threadIdx.x; idx < n; idx += 1024)
        s += partials[idx];
    #pragma unroll
    for (int m = 1; m < 64; m <<= 1)
        s += __shfl_xor(s, m, 64);
    __shared__ float lds[1024 / 64];
    if ((threadIdx.x & 63) == 0) lds[threadIdx.x >> 6] = s;
    __syncthreads();
    if (threadIdx.x == 0) {
        float tot = 0.f;
        #pragma unroll
        for (int q = 0; q < 1024 / 64; ++q) tot += lds[q];
        out[0] = tot / (float)NTRIP;
    }
}

extern "C" void kernel_launch(void* const* d_in, const int* in_sizes, int n_in,
                              void* d_out, int out_size, void* d_ws, size_t ws_size,
                              hipStream_t stream) {
    const float* x    = (const float*)d_in[0];
    const int*   trip = (const int*)d_in[1];
    float*       out  = (float*)d_out;

    const size_t need = XQ_BYTES + (size_t)NSLOT * SLOT_STRIDE * 4 + 64;
    if (ws_size >= need) {
        uint4*        xq      = (uint4*)d_ws;
        float*        slots   = (float*)((char*)d_ws + XQ_BYTES);
        unsigned int* counter = (unsigned int*)((char*)d_ws + XQ_BYTES
                                 + (size_t)NSLOT * SLOT_STRIDE * 4);
        convert8_kernel<<<(NROWS * DIM / 16) / 256, 256, 0, stream>>>(
            (const float4*)x, xq, slots, counter);
        gather8_kernel<<<NBLK, 256, 0, stream>>>(xq, trip, slots,
                                                 counter, out);
    } else {
        float* partials = (float*)d_ws;   // 16384 floats
        triplet_partial_f32<<<NTRIP / 4, 256, 0, stream>>>(x, trip, partials);
        reduce_kernel<<<1, 1024, 0, stream>>>(partials, out, NTRIP / 4);
    }
}

// Round 9
// 59.951 us; speedup vs baseline: 1.0192x; 1.0192x over previous
//
#include <hip/hip_runtime.h>

// TripletLoss: N=8192, D=512, T=65536
//   loss = mean_t softplus(||x_i - x_j||^2 - ||x_i - x_k||^2)
//
// Round 9: r8 (2-kernel fused-slot reduction) + amdgpu_waves_per_eu(4,4)
// pin on the gather kernel. r8's regression was the compiler down-allocating
// to 60 VGPRs (chasing 8 waves/EU) and serializing the 12 in-flight gather
// loads; pinning 4 waves/EU grants the 128-VGPR budget that r6/r7 enjoyed.

typedef float floatx2 __attribute__((ext_vector_type(2)));

#define NTRIP 65536
#define DIM   512
#define NROWS 8192
#define WPB   4                    // waves per block
#define UNR   8                    // triplets per wave
#define TPB   (WPB * UNR)          // 32
#define NBLK  (NTRIP / TPB)        // 2048
#define XQ_BYTES ((size_t)NROWS * DIM)   // 4 MiB
#define NSLOT 64
#define SLOT_STRIDE 16             // floats; 64 B apart

__device__ __forceinline__ float softplus_stable(float z) {
    return fmaxf(z, 0.f) + log1pf(expf(-fabsf(z)));
}

__device__ __forceinline__ unsigned int enc4(float a, float b, float c, float d) {
    unsigned int w = __builtin_amdgcn_cvt_pk_fp8_f32(a, b, 0, false);
    w = __builtin_amdgcn_cvt_pk_fp8_f32(c, d, w, true);
    return w;
}

__device__ __forceinline__ void decode4(unsigned int w, float* f) {
    floatx2 p0 = __builtin_amdgcn_cvt_pk_f32_fp8(w, false);
    floatx2 p1 = __builtin_amdgcn_cvt_pk_f32_fp8(w, true);
    f[0] = p0.x; f[1] = p0.y; f[2] = p1.x; f[3] = p1.y;
}

__device__ __forceinline__ void decode16(uint4 v, float* f) {
    decode4(v.x, f);  decode4(v.y, f + 4);
    decode4(v.z, f + 8); decode4(v.w, f + 12);
}

// ------- Kernel A: fp32 -> fp8 (16 elems/thread); zero slots+counter -------
__global__ __launch_bounds__(256) void convert8_kernel(
    const float4* __restrict__ x, uint4* __restrict__ xq,
    float* __restrict__ slots, unsigned int* __restrict__ counter)
{
    if (blockIdx.x == 0) {
        if (threadIdx.x < NSLOT) slots[threadIdx.x * SLOT_STRIDE] = 0.f;
        if (threadIdx.x == NSLOT) *counter = 0u;
    }
    const int idx = blockIdx.x * 256 + threadIdx.x;
    float4 a = x[(size_t)idx * 4 + 0];
    float4 b = x[(size_t)idx * 4 + 1];
    float4 c = x[(size_t)idx * 4 + 2];
    float4 d = x[(size_t)idx * 4 + 3];
    uint4 o;
    o.x = enc4(a.x, a.y, a.z, a.w);
    o.y = enc4(b.x, b.y, b.z, b.w);
    o.z = enc4(c.x, c.y, c.z, c.w);
    o.w = enc4(d.x, d.y, d.z, d.w);
    xq[idx] = o;
}

// ---- Kernel B: fp8 gather + loss + fused last-block final reduction ----
__global__ __launch_bounds__(256)
__attribute__((amdgpu_waves_per_eu(4, 4)))
void gather8_kernel(
    const uint4* __restrict__ xq,     // row stride = 32 uint4 (512 B)
    const int*   __restrict__ trip,
    float*       __restrict__ slots,
    unsigned int* __restrict__ counter,
    float*       __restrict__ out)
{
    const int lane = threadIdx.x & 63;
    const int half = lane >> 5;        // 0: even triplet of pair; 1: odd
    const int l5   = lane & 31;        // 16B slot within row
    const int wib  = threadIdx.x >> 6;
    const int t0   = (blockIdx.x * WPB + wib) * UNR;

    // 24 indices via 6 wave-uniform int4 loads
    const int4* tp = (const int4*)(trip + 3 * t0);
    int4 w0 = tp[0], w1 = tp[1], w2 = tp[2];
    int4 w3 = tp[3], w4 = tp[4], w5 = tp[5];
    const int id[24] = { w0.x, w0.y, w0.z, w0.w, w1.x, w1.y, w1.z, w1.w,
                         w2.x, w2.y, w2.z, w2.w, w3.x, w3.y, w3.z, w3.w,
                         w4.x, w4.y, w4.z, w4.w, w5.x, w5.y, w5.z, w5.w };

    // 12 load instructions, each fetching two rows (one per 32-lane half).
    uint4 r[4][3];
    #pragma unroll
    for (int g = 0; g < 4; ++g) {
        #pragma unroll
        for (int m = 0; m < 3; ++m) {
            const int row = half ? id[3 * (2 * g + 1) + m]
                                 : id[3 * (2 * g) + m];
            r[g][m] = xq[(size_t)row * 32 + l5];
        }
    }

    float z[4] = {0.f, 0.f, 0.f, 0.f};
    #pragma unroll
    for (int g = 0; g < 4; ++g) {
        float fa[16], fb[16], fc[16];
        decode16(r[g][0], fa);
        decode16(r[g][1], fb);
        decode16(r[g][2], fc);
        #pragma unroll
        for (int e = 0; e < 16; ++e) {
            float d = fa[e] - fb[e];
            float q = fa[e] - fc[e];
            z[g] += d * d - q * q;
        }
    }

    // reduce within each 32-lane half (xor masks 1..16 stay inside a half)
    #pragma unroll
    for (int m = 1; m <= 16; m <<= 1) {
        #pragma unroll
        for (int g = 0; g < 4; ++g)
            z[g] += __shfl_xor(z[g], m, 64);
    }

    float sp = (softplus_stable(z[0]) + softplus_stable(z[1])) +
               (softplus_stable(z[2]) + softplus_stable(z[3]));
    sp += __shfl_xor(sp, 32, 64);      // wave total over 8 triplets

    __shared__ float wsum[WPB];
    if (lane == 0) wsum[wib] = sp;
    __syncthreads();

    __shared__ bool amlast;
    if (threadIdx.x == 0) {
        float bs = (wsum[0] + wsum[1]) + (wsum[2] + wsum[3]);
        // device-scope atomic lands at L2 (coherent); spread slots avoid
        // same-address serialization (<=32 adds per slot)
        atomicAdd(&slots[(blockIdx.x & (NSLOT - 1)) * SLOT_STRIDE], bs);
        // release: slot add ordered before counter bump; acquire on read
        unsigned int prev = __hip_atomic_fetch_add(
            counter, 1u, __ATOMIC_ACQ_REL, __HIP_MEMORY_SCOPE_AGENT);
        amlast = (prev == NBLK - 1);
    }
    __syncthreads();

    if (amlast) {
        // last block: sum the 64 slots (atomic loads -> L2-coherent)
        if (threadIdx.x < NSLOT) {
            float v = __hip_atomic_load(
                &slots[threadIdx.x * SLOT_STRIDE],
                __ATOMIC_RELAXED, __HIP_MEMORY_SCOPE_AGENT);
            #pragma unroll
            for (int m = 1; m < NSLOT; m <<= 1)
                v += __shfl_xor(v, m, 64);
            if (threadIdx.x == 0)
                out[0] = v / (float)NTRIP;
        }
    }
}

// ---------------- fp32 fallback path (proven) ----------------
__global__ __launch_bounds__(256) void triplet_partial_f32(
    const float* __restrict__ x,
    const int*   __restrict__ trip,
    float*       __restrict__ partials)
{
    const int lane = threadIdx.x & 63;
    const int wib  = threadIdx.x >> 6;
    const int t    = blockIdx.x * 4 + wib;
    const int i = trip[3 * t + 0];
    const int j = trip[3 * t + 1];
    const int k = trip[3 * t + 2];
    const float4* pi = (const float4*)(x + (size_t)i * DIM) + lane * 2;
    const float4* pj = (const float4*)(x + (size_t)j * DIM) + lane * 2;
    const float4* pk = (const float4*)(x + (size_t)k * DIM) + lane * 2;
    float4 a0 = pi[0], a1 = pi[1];
    float4 b0 = pj[0], b1 = pj[1];
    float4 c0 = pk[0], c1 = pk[1];
    float z = 0.f;
    {
        float d;
        d = a0.x-b0.x; z += d*d; d = a0.y-b0.y; z += d*d;
        d = a0.z-b0.z; z += d*d; d = a0.w-b0.w; z += d*d;
        d = a1.x-b1.x; z += d*d; d = a1.y-b1.y; z += d*d;
        d = a1.z-b1.z; z += d*d; d = a1.w-b1.w; z += d*d;
        d = a0.x-c0.x; z -= d*d; d = a0.y-c0.y; z -= d*d;
        d = a0.z-c0.z; z -= d*d; d = a0.w-c0.w; z -= d*d;
        d = a1.x-c1.x; z -= d*d; d = a1.y-c1.y; z -= d*d;
        d = a1.z-c1.z; z -= d*d; d = a1.w-c1.w; z -= d*d;
    }
    #pragma unroll
    for (int m = 1; m < 64; m <<= 1) z += __shfl_xor(z, m, 64);
    __shared__ float wsum[4];
    if (lane == 0) wsum[wib] = softplus_stable(z);
    __syncthreads();
    if (threadIdx.x == 0)
        partials[blockIdx.x] = (wsum[0] + wsum[1]) + (wsum[2] + wsum[3]);
}

__global__ __launch_bounds__(1024) void reduce_kernel(
    const float* __restrict__ partials, float* __restrict__ out, int n)
{
    float s = 0.f;
    for (int idx = threadIdx.x; idx < n; idx += 1024)
        s += partials[idx];
    #pragma unroll
    for (int m = 1; m < 64; m <<= 1)
        s += __shfl_xor(s, m, 64);
    __shared__ float lds[1024 / 64];
    if ((threadIdx.x & 63) == 0) lds[threadIdx.x >> 6] = s;
    __syncthreads();
    if (threadIdx.x == 0) {
        float tot = 0.f;
        #pragma unroll
        for (int q = 0; q < 1024 / 64; ++q) tot += lds[q];
        out[0] = tot / (float)NTRIP;
    }
}

extern "C" void kernel_launch(void* const* d_in, const int* in_sizes, int n_in,
                              void* d_out, int out_size, void* d_ws, size_t ws_size,
                              hipStream_t stream) {
    const float* x    = (const float*)d_in[0];
    const int*   trip = (const int*)d_in[1];
    float*       out  = (float*)d_out;

    const size_t need = XQ_BYTES + (size_t)NSLOT * SLOT_STRIDE * 4 + 64;
    if (ws_size >= need) {
        uint4*        xq      = (uint4*)d_ws;
        float*        slots   = (float*)((char*)d_ws + XQ_BYTES);
        unsigned int* counter = (unsigned int*)((char*)d_ws + XQ_BYTES
                                 + (size_t)NSLOT * SLOT_STRIDE * 4);
        convert8_kernel<<<(NROWS * DIM / 16) / 256, 256, 0, stream>>>(
            (const float4*)x, xq, slots, counter);
        gather8_kernel<<<NBLK, 256, 0, stream>>>(xq, trip, slots,
                                                 counter, out);
    } else {
        float* partials = (float*)d_ws;   // 16384 floats
        triplet_partial_f32<<<NTRIP / 4, 256, 0, stream>>>(x, trip, partials);
        reduce_kernel<<<1, 1024, 0, stream>>>(partials, out, NTRIP / 4);
    }
}

// Round 10
// 29.928 us; speedup vs baseline: 2.0417x; 2.0032x over previous
//
#include <hip/hip_runtime.h>

// TripletLoss: N=8192, D=512, T=65536
//   loss = mean_t softplus(||x_i - x_j||^2 - ||x_i - x_k||^2)
//
// Round 10: LDS-slice restructure. The random row-gather is latency-capped
// at the L2 request queues (~20 us for 96 MB; UNR 4->8 was neutral), so move
// the random access into LDS:
//   A: fp32 -> fp8 e4m3, SLICE-MAJOR layout xq_s[s][row] (16 B per row-slice);
//      also zeroes the 64 reduce slots + done counter.
//   B: 256 blocks = 32 slices x 8 triplet-groups. Stage slice (128 KB,
//      contiguous) into LDS; each lane: 1 triplet/iter, 3 random
//      ds_read_b128, decode fp8, partial z -> zp[s][t] (coalesced).
//   C: 64 blocks sum zp over slices (streaming), softplus, one atomicAdd
//      per block into its own slot (deterministic), last block sums slots.
// Fallback tiers: ws < 12.01 MB -> r7 path (proven 30.2 us); < 4.07 MB -> fp32.

typedef float floatx2 __attribute__((ext_vector_type(2)));

#define NTRIP  65536
#define DIM    512
#define NROWS  8192
#define NSLICE 32                  // 16 B of fp8 per row per slice
#define SLICE_U4 NROWS             // uint4 per slice
#define GGRP   8                   // triplet groups
#define TRIP_PER_G (NTRIP / GGRP)  // 8192
#define BT     512                 // kernel B block size
#define NSLOT  64
#define SLOT_STRIDE 16             // floats; 64 B apart

// ws layout (new path): xq_s 4 MB | zp 8 MB | slots 4 KB | counter
#define XQS_BYTES ((size_t)NSLICE * SLICE_U4 * 16)      // 4 MiB
#define ZP_BYTES  ((size_t)NSLICE * NTRIP * 4)          // 8 MiB
#define NEED_NEW  (XQS_BYTES + ZP_BYTES + NSLOT * SLOT_STRIDE * 4 + 64)
// r7 path: xq row-major 4 MB + partials
#define XQ_BYTES  ((size_t)NROWS * DIM)
#define R7_NBLK   2048
#define NEED_R7   (XQ_BYTES + (size_t)R7_NBLK * 4)

__device__ __forceinline__ float softplus_stable(float z) {
    return fmaxf(z, 0.f) + log1pf(expf(-fabsf(z)));
}

__device__ __forceinline__ unsigned int enc4(float a, float b, float c, float d) {
    unsigned int w = __builtin_amdgcn_cvt_pk_fp8_f32(a, b, 0, false);
    w = __builtin_amdgcn_cvt_pk_fp8_f32(c, d, w, true);
    return w;
}

__device__ __forceinline__ void decode4(unsigned int w, float* f) {
    floatx2 p0 = __builtin_amdgcn_cvt_pk_f32_fp8(w, false);
    floatx2 p1 = __builtin_amdgcn_cvt_pk_f32_fp8(w, true);
    f[0] = p0.x; f[1] = p0.y; f[2] = p1.x; f[3] = p1.y;
}

__device__ __forceinline__ void decode16(uint4 v, float* f) {
    decode4(v.x, f);     decode4(v.y, f + 4);
    decode4(v.z, f + 8); decode4(v.w, f + 12);
}

// ====================== NEW PATH (LDS slice) ======================

// Kernel A: fp32 -> fp8, slice-major. thread idx = s*8192 + r.
// Reads 64 B contiguous per lane (full cacheline); writes contiguous.
__global__ __launch_bounds__(256) void convert_slice_kernel(
    const float4* __restrict__ x, uint4* __restrict__ xq_s,
    float* __restrict__ slots, unsigned int* __restrict__ counter)
{
    if (blockIdx.x == 0) {
        if (threadIdx.x < NSLOT) slots[threadIdx.x * SLOT_STRIDE] = 0.f;
        if (threadIdx.x == NSLOT) *counter = 0u;
    }
    const int idx = blockIdx.x * 256 + threadIdx.x;   // 0 .. 262143
    const int s   = idx >> 13;                        // slice
    const int r   = idx & (NROWS - 1);                // row
    const float4* src = x + (size_t)r * (DIM / 4) + s * 4;
    float4 a = src[0], b = src[1], c = src[2], d = src[3];
    uint4 o;
    o.x = enc4(a.x, a.y, a.z, a.w);
    o.y = enc4(b.x, b.y, b.z, b.w);
    o.z = enc4(c.x, c.y, c.z, c.w);
    o.w = enc4(d.x, d.y, d.z, d.w);
    xq_s[idx] = o;                                    // = s*8192 + r
}

// Kernel B: stage one slice in LDS, random-access it per triplet.
__global__ __launch_bounds__(BT) void slice_gather_kernel(
    const uint4* __restrict__ xq_s,
    const int*   __restrict__ trip,
    float*       __restrict__ zp)
{
    __shared__ uint4 sl[SLICE_U4];                    // 128 KiB
    const int s   = blockIdx.x & (NSLICE - 1);
    const int g   = blockIdx.x >> 5;
    const int tid = threadIdx.x;

    // stage slice s (contiguous 128 KB), coalesced
    const uint4* src = xq_s + (size_t)s * SLICE_U4;
    #pragma unroll
    for (int q = 0; q < SLICE_U4 / BT; ++q)           // 16
        sl[tid + q * BT] = src[tid + q * BT];
    __syncthreads();

    float* zrow = zp + (size_t)s * NTRIP;
    const int tbase = g * TRIP_PER_G;
    for (int it = 0; it < TRIP_PER_G / BT; ++it) {    // 16
        const int t = tbase + it * BT + tid;
        const int i = trip[3 * t + 0];
        const int j = trip[3 * t + 1];
        const int k = trip[3 * t + 2];
        uint4 ra = sl[i], rb = sl[j], rc = sl[k];     // random ds_read_b128
        float fa[16], fb[16], fc[16];
        decode16(ra, fa); decode16(rb, fb); decode16(rc, fc);
        float zz = 0.f;
        #pragma unroll
        for (int e = 0; e < 16; ++e) {
            float d = fa[e] - fb[e];
            float q = fa[e] - fc[e];
            zz += d * d - q * q;
        }
        zrow[t] = zz;                                 // coalesced
    }
}

// Kernel C: combine slices, softplus, deterministic slot reduce.
__global__ __launch_bounds__(256) void combine_kernel(
    const float* __restrict__ zp,
    float*       __restrict__ slots,
    unsigned int* __restrict__ counter,
    float*       __restrict__ out)
{
    const int tid = threadIdx.x;
    float sp = 0.f;
    #pragma unroll
    for (int u = 0; u < 4; ++u) {
        const int t = blockIdx.x * 1024 + u * 256 + tid;
        float z = 0.f;
        #pragma unroll
        for (int s = 0; s < NSLICE; ++s)
            z += zp[(size_t)s * NTRIP + t];
        sp += softplus_stable(z);
    }
    #pragma unroll
    for (int m = 1; m < 64; m <<= 1)
        sp += __shfl_xor(sp, m, 64);

    __shared__ float ws[256 / 64];
    if ((tid & 63) == 0) ws[tid >> 6] = sp;
    __syncthreads();

    __shared__ bool amlast;
    if (tid == 0) {
        float bs = (ws[0] + ws[1]) + (ws[2] + ws[3]);
        // exactly one add per slot (64 blocks, 64 slots) -> deterministic
        atomicAdd(&slots[blockIdx.x * SLOT_STRIDE], bs);
        unsigned int prev = __hip_atomic_fetch_add(
            counter, 1u, __ATOMIC_ACQ_REL, __HIP_MEMORY_SCOPE_AGENT);
        amlast = (prev == 63);
    }
    __syncthreads();

    if (amlast && tid < NSLOT) {
        float v = __hip_atomic_load(&slots[tid * SLOT_STRIDE],
                                    __ATOMIC_RELAXED, __HIP_MEMORY_SCOPE_AGENT);
        #pragma unroll
        for (int m = 1; m < NSLOT; m <<= 1)
            v += __shfl_xor(v, m, 64);
        if (tid == 0) out[0] = v / (float)NTRIP;
    }
}

// ====================== r7 PATH (proven 30.2 us) ======================

__global__ __launch_bounds__(256) void convert8_row_kernel(
    const float4* __restrict__ x, uint4* __restrict__ xq)
{
    const int idx = blockIdx.x * 256 + threadIdx.x;
    float4 a = x[(size_t)idx * 4 + 0];
    float4 b = x[(size_t)idx * 4 + 1];
    float4 c = x[(size_t)idx * 4 + 2];
    float4 d = x[(size_t)idx * 4 + 3];
    uint4 o;
    o.x = enc4(a.x, a.y, a.z, a.w);
    o.y = enc4(b.x, b.y, b.z, b.w);
    o.z = enc4(c.x, c.y, c.z, c.w);
    o.w = enc4(d.x, d.y, d.z, d.w);
    xq[idx] = o;
}

__global__ __launch_bounds__(256, 4) void gather8_kernel(
    const uint4* __restrict__ xq,
    const int*   __restrict__ trip,
    float*       __restrict__ partials)
{
    const int lane = threadIdx.x & 63;
    const int half = lane >> 5;
    const int l5   = lane & 31;
    const int wib  = threadIdx.x >> 6;
    const int t0   = (blockIdx.x * 4 + wib) * 8;

    const int4* tp = (const int4*)(trip + 3 * t0);
    int4 w0 = tp[0], w1 = tp[1], w2 = tp[2];
    int4 w3 = tp[3], w4 = tp[4], w5 = tp[5];
    const int id[24] = { w0.x, w0.y, w0.z, w0.w, w1.x, w1.y, w1.z, w1.w,
                         w2.x, w2.y, w2.z, w2.w, w3.x, w3.y, w3.z, w3.w,
                         w4.x, w4.y, w4.z, w4.w, w5.x, w5.y, w5.z, w5.w };

    uint4 r[4][3];
    #pragma unroll
    for (int g = 0; g < 4; ++g) {
        #pragma unroll
        for (int m = 0; m < 3; ++m) {
            const int row = half ? id[3 * (2 * g + 1) + m]
                                 : id[3 * (2 * g) + m];
            r[g][m] = xq[(size_t)row * 32 + l5];
        }
    }

    float z[4] = {0.f, 0.f, 0.f, 0.f};
    #pragma unroll
    for (int g = 0; g < 4; ++g) {
        float fa[16], fb[16], fc[16];
        decode16(r[g][0], fa);
        decode16(r[g][1], fb);
        decode16(r[g][2], fc);
        #pragma unroll
        for (int e = 0; e < 16; ++e) {
            float d = fa[e] - fb[e];
            float q = fa[e] - fc[e];
            z[g] += d * d - q * q;
        }
    }

    #pragma unroll
    for (int m = 1; m <= 16; m <<= 1) {
        #pragma unroll
        for (int g = 0; g < 4; ++g)
            z[g] += __shfl_xor(z[g], m, 64);
    }

    float sp = (softplus_stable(z[0]) + softplus_stable(z[1])) +
               (softplus_stable(z[2]) + softplus_stable(z[3]));
    sp += __shfl_xor(sp, 32, 64);

    __shared__ float wsum[4];
    if (lane == 0) wsum[wib] = sp;
    __syncthreads();
    if (threadIdx.x == 0)
        partials[blockIdx.x] = (wsum[0] + wsum[1]) + (wsum[2] + wsum[3]);
}

__global__ __launch_bounds__(1024) void reduce_kernel(
    const float* __restrict__ partials, float* __restrict__ out, int n)
{
    float s = 0.f;
    for (int idx = threadIdx.x; idx < n; idx += 1024)
        s += partials[idx];
    #pragma unroll
    for (int m = 1; m < 64; m <<= 1)
        s += __shfl_xor(s, m, 64);
    __shared__ float lds[1024 / 64];
    if ((threadIdx.x & 63) == 0) lds[threadIdx.x >> 6] = s;
    __syncthreads();
    if (threadIdx.x == 0) {
        float tot = 0.f;
        #pragma unroll
        for (int q = 0; q < 1024 / 64; ++q) tot += lds[q];
        out[0] = tot / (float)NTRIP;
    }
}

// ====================== fp32 fallback ======================
__global__ __launch_bounds__(256) void triplet_partial_f32(
    const float* __restrict__ x,
    const int*   __restrict__ trip,
    float*       __restrict__ partials)
{
    const int lane = threadIdx.x & 63;
    const int wib  = threadIdx.x >> 6;
    const int t    = blockIdx.x * 4 + wib;
    const int i = trip[3 * t + 0];
    const int j = trip[3 * t + 1];
    const int k = trip[3 * t + 2];
    const float4* pi = (const float4*)(x + (size_t)i * DIM) + lane * 2;
    const float4* pj = (const float4*)(x + (size_t)j * DIM) + lane * 2;
    const float4* pk = (const float4*)(x + (size_t)k * DIM) + lane * 2;
    float4 a0 = pi[0], a1 = pi[1];
    float4 b0 = pj[0], b1 = pj[1];
    float4 c0 = pk[0], c1 = pk[1];
    float z = 0.f;
    {
        float d;
        d = a0.x-b0.x; z += d*d; d = a0.y-b0.y; z += d*d;
        d = a0.z-b0.z; z += d*d; d = a0.w-b0.w; z += d*d;
        d = a1.x-b1.x; z += d*d; d = a1.y-b1.y; z += d*d;
        d = a1.z-b1.z; z += d*d; d = a1.w-b1.w; z += d*d;
        d = a0.x-c0.x; z -= d*d; d = a0.y-c0.y; z -= d*d;
        d = a0.z-c0.z; z -= d*d; d = a0.w-c0.w; z -= d*d;
        d = a1.x-c1.x; z -= d*d; d = a1.y-c1.y; z -= d*d;
        d = a1.z-c1.z; z -= d*d; d = a1.w-c1.w; z -= d*d;
    }
    #pragma unroll
    for (int m = 1; m < 64; m <<= 1) z += __shfl_xor(z, m, 64);
    __shared__ float wsum[4];
    if (lane == 0) wsum[wib] = softplus_stable(z);
    __syncthreads();
    if (threadIdx.x == 0)
        partials[blockIdx.x] = (wsum[0] + wsum[1]) + (wsum[2] + wsum[3]);
}

extern "C" void kernel_launch(void* const* d_in, const int* in_sizes, int n_in,
                              void* d_out, int out_size, void* d_ws, size_t ws_size,
                              hipStream_t stream) {
    const float* x    = (const float*)d_in[0];
    const int*   trip = (const int*)d_in[1];
    float*       out  = (float*)d_out;

    if (ws_size >= NEED_NEW) {
        uint4*        xq_s    = (uint4*)d_ws;
        float*        zp      = (float*)((char*)d_ws + XQS_BYTES);
        float*        slots   = (float*)((char*)d_ws + XQS_BYTES + ZP_BYTES);
        unsigned int* counter = (unsigned int*)((char*)d_ws + XQS_BYTES
                                 + ZP_BYTES + NSLOT * SLOT_STRIDE * 4);
        convert_slice_kernel<<<(NROWS * NSLICE) / 256, 256, 0, stream>>>(
            (const float4*)x, xq_s, slots, counter);
        slice_gather_kernel<<<NSLICE * GGRP, BT, 0, stream>>>(xq_s, trip, zp);
        combine_kernel<<<NSLOT, 256, 0, stream>>>(zp, slots, counter, out);
    } else if (ws_size >= NEED_R7) {
        uint4* xq       = (uint4*)d_ws;
        float* partials = (float*)((char*)d_ws + XQ_BYTES);
        convert8_row_kernel<<<(NROWS * DIM / 16) / 256, 256, 0, stream>>>(
            (const float4*)x, xq);
        gather8_kernel<<<R7_NBLK, 256, 0, stream>>>(xq, trip, partials);
        reduce_kernel<<<1, 1024, 0, stream>>>(partials, out, R7_NBLK);
    } else {
        float* partials = (float*)d_ws;
        triplet_partial_f32<<<NTRIP / 4, 256, 0, stream>>>(x, trip, partials);
        reduce_kernel<<<1, 1024, 0, stream>>>(partials, out, NTRIP / 4);
    }
}

// Round 11
// 27.468 us; speedup vs baseline: 2.2245x; 1.0895x over previous
//
#include <hip/hip_runtime.h>

// TripletLoss: N=8192, D=512, T=65536
//   loss = mean_t softplus(||x_i - x_j||^2 - ||x_i - x_k||^2)
//
// Round 11: r10 LDS-slice structure + latency fixes in kernel B:
//   - BT 512 -> 1024 (4 waves/SIMD instead of 2: 2x TLP)
//   - software-pipelined triplet-index prefetch (global load latency hides
//     under current iteration's ds_read + VALU)
//   A: fp32 -> fp8 e4m3 slice-major (16B/row/slice); zero slots+counter.
//   B: 256 blocks (32 slices x 8 groups), stage 128 KiB slice in LDS,
//      1 triplet/thread/iter, 3 random ds_read_b128, zp[s][t] coalesced.
//   C: 64 blocks combine slices + softplus + slot reduce (1 add/slot).
// Fallback tiers: ws < 12.01 MB -> r7 path (proven 30.2); < 4.07 MB -> fp32.

typedef float floatx2 __attribute__((ext_vector_type(2)));

#define NTRIP  65536
#define DIM    512
#define NROWS  8192
#define NSLICE 32                  // 16 B of fp8 per row per slice
#define SLICE_U4 NROWS             // uint4 per slice
#define GGRP   8                   // triplet groups
#define TRIP_PER_G (NTRIP / GGRP)  // 8192
#define BT     1024                // kernel B block size (16 waves)
#define NSLOT  64
#define SLOT_STRIDE 16             // floats; 64 B apart

#define XQS_BYTES ((size_t)NSLICE * SLICE_U4 * 16)      // 4 MiB
#define ZP_BYTES  ((size_t)NSLICE * NTRIP * 4)          // 8 MiB
#define NEED_NEW  (XQS_BYTES + ZP_BYTES + NSLOT * SLOT_STRIDE * 4 + 64)
#define XQ_BYTES  ((size_t)NROWS * DIM)
#define R7_NBLK   2048
#define NEED_R7   (XQ_BYTES + (size_t)R7_NBLK * 4)

__device__ __forceinline__ float softplus_stable(float z) {
    return fmaxf(z, 0.f) + log1pf(expf(-fabsf(z)));
}

__device__ __forceinline__ unsigned int enc4(float a, float b, float c, float d) {
    unsigned int w = __builtin_amdgcn_cvt_pk_fp8_f32(a, b, 0, false);
    w = __builtin_amdgcn_cvt_pk_fp8_f32(c, d, w, true);
    return w;
}

__device__ __forceinline__ void decode4(unsigned int w, float* f) {
    floatx2 p0 = __builtin_amdgcn_cvt_pk_f32_fp8(w, false);
    floatx2 p1 = __builtin_amdgcn_cvt_pk_f32_fp8(w, true);
    f[0] = p0.x; f[1] = p0.y; f[2] = p1.x; f[3] = p1.y;
}

__device__ __forceinline__ void decode16(uint4 v, float* f) {
    decode4(v.x, f);     decode4(v.y, f + 4);
    decode4(v.z, f + 8); decode4(v.w, f + 12);
}

// ====================== NEW PATH (LDS slice) ======================

__global__ __launch_bounds__(256) void convert_slice_kernel(
    const float4* __restrict__ x, uint4* __restrict__ xq_s,
    float* __restrict__ slots, unsigned int* __restrict__ counter)
{
    if (blockIdx.x == 0) {
        if (threadIdx.x < NSLOT) slots[threadIdx.x * SLOT_STRIDE] = 0.f;
        if (threadIdx.x == NSLOT) *counter = 0u;
    }
    const int idx = blockIdx.x * 256 + threadIdx.x;   // 0 .. 262143
    const int s   = idx >> 13;                        // slice
    const int r   = idx & (NROWS - 1);                // row
    const float4* src = x + (size_t)r * (DIM / 4) + s * 4;
    float4 a = src[0], b = src[1], c = src[2], d = src[3];
    uint4 o;
    o.x = enc4(a.x, a.y, a.z, a.w);
    o.y = enc4(b.x, b.y, b.z, b.w);
    o.z = enc4(c.x, c.y, c.z, c.w);
    o.w = enc4(d.x, d.y, d.z, d.w);
    xq_s[idx] = o;                                    // = s*8192 + r
}

__global__ __launch_bounds__(BT) void slice_gather_kernel(
    const uint4* __restrict__ xq_s,
    const int*   __restrict__ trip,
    float*       __restrict__ zp)
{
    __shared__ uint4 sl[SLICE_U4];                    // 128 KiB
    const int s   = blockIdx.x & (NSLICE - 1);
    const int g   = blockIdx.x >> 5;
    const int tid = threadIdx.x;

    // stage slice s (contiguous 128 KB), coalesced
    const uint4* src = xq_s + (size_t)s * SLICE_U4;
    #pragma unroll
    for (int q = 0; q < SLICE_U4 / BT; ++q)           // 8
        sl[tid + q * BT] = src[tid + q * BT];
    __syncthreads();

    float* zrow = zp + (size_t)s * NTRIP;
    const int tbase = g * TRIP_PER_G + tid;

    // software-pipelined index prefetch: global latency of iteration it+1's
    // indices hides under iteration it's ds_read + VALU
    int ci = trip[3 * tbase + 0];
    int cj = trip[3 * tbase + 1];
    int ck = trip[3 * tbase + 2];
    for (int it = 0; it < TRIP_PER_G / BT; ++it) {    // 8
        int ni = 0, nj = 0, nk = 0;
        if (it + 1 < TRIP_PER_G / BT) {
            const int tn = tbase + (it + 1) * BT;
            ni = trip[3 * tn + 0];
            nj = trip[3 * tn + 1];
            nk = trip[3 * tn + 2];
        }
        uint4 ra = sl[ci], rb = sl[cj], rc = sl[ck];  // random ds_read_b128
        float fa[16], fb[16], fc[16];
        decode16(ra, fa); decode16(rb, fb); decode16(rc, fc);
        float zz = 0.f;
        #pragma unroll
        for (int e = 0; e < 16; ++e) {
            float d = fa[e] - fb[e];
            float q = fa[e] - fc[e];
            zz += d * d - q * q;
        }
        zrow[tbase + it * BT] = zz;                   // coalesced
        ci = ni; cj = nj; ck = nk;
    }
}

__global__ __launch_bounds__(256) void combine_kernel(
    const float* __restrict__ zp,
    float*       __restrict__ slots,
    unsigned int* __restrict__ counter,
    float*       __restrict__ out)
{
    const int tid = threadIdx.x;
    float sp = 0.f;
    #pragma unroll
    for (int u = 0; u < 4; ++u) {
        const int t = blockIdx.x * 1024 + u * 256 + tid;
        float z = 0.f;
        #pragma unroll
        for (int s = 0; s < NSLICE; ++s)
            z += zp[(size_t)s * NTRIP + t];
        sp += softplus_stable(z);
    }
    #pragma unroll
    for (int m = 1; m < 64; m <<= 1)
        sp += __shfl_xor(sp, m, 64);

    __shared__ float ws[256 / 64];
    if ((tid & 63) == 0) ws[tid >> 6] = sp;
    __syncthreads();

    __shared__ bool amlast;
    if (tid == 0) {
        float bs = (ws[0] + ws[1]) + (ws[2] + ws[3]);
        atomicAdd(&slots[blockIdx.x * SLOT_STRIDE], bs);  // 1 add per slot
        unsigned int prev = __hip_atomic_fetch_add(
            counter, 1u, __ATOMIC_ACQ_REL, __HIP_MEMORY_SCOPE_AGENT);
        amlast = (prev == 63);
    }
    __syncthreads();

    if (amlast && tid < NSLOT) {
        float v = __hip_atomic_load(&slots[tid * SLOT_STRIDE],
                                    __ATOMIC_RELAXED, __HIP_MEMORY_SCOPE_AGENT);
        #pragma unroll
        for (int m = 1; m < NSLOT; m <<= 1)
            v += __shfl_xor(v, m, 64);
        if (tid == 0) out[0] = v / (float)NTRIP;
    }
}

// ====================== r7 PATH (proven 30.2 us) ======================

__global__ __launch_bounds__(256) void convert8_row_kernel(
    const float4* __restrict__ x, uint4* __restrict__ xq)
{
    const int idx = blockIdx.x * 256 + threadIdx.x;
    float4 a = x[(size_t)idx * 4 + 0];
    float4 b = x[(size_t)idx * 4 + 1];
    float4 c = x[(size_t)idx * 4 + 2];
    float4 d = x[(size_t)idx * 4 + 3];
    uint4 o;
    o.x = enc4(a.x, a.y, a.z, a.w);
    o.y = enc4(b.x, b.y, b.z, b.w);
    o.z = enc4(c.x, c.y, c.z, c.w);
    o.w = enc4(d.x, d.y, d.z, d.w);
    xq[idx] = o;
}

__global__ __launch_bounds__(256, 4) void gather8_kernel(
    const uint4* __restrict__ xq,
    const int*   __restrict__ trip,
    float*       __restrict__ partials)
{
    const int lane = threadIdx.x & 63;
    const int half = lane >> 5;
    const int l5   = lane & 31;
    const int wib  = threadIdx.x >> 6;
    const int t0   = (blockIdx.x * 4 + wib) * 8;

    const int4* tp = (const int4*)(trip + 3 * t0);
    int4 w0 = tp[0], w1 = tp[1], w2 = tp[2];
    int4 w3 = tp[3], w4 = tp[4], w5 = tp[5];
    const int id[24] = { w0.x, w0.y, w0.z, w0.w, w1.x, w1.y, w1.z, w1.w,
                         w2.x, w2.y, w2.z, w2.w, w3.x, w3.y, w3.z, w3.w,
                         w4.x, w4.y, w4.z, w4.w, w5.x, w5.y, w5.z, w5.w };

    uint4 r[4][3];
    #pragma unroll
    for (int g = 0; g < 4; ++g) {
        #pragma unroll
        for (int m = 0; m < 3; ++m) {
            const int row = half ? id[3 * (2 * g + 1) + m]
                                 : id[3 * (2 * g) + m];
            r[g][m] = xq[(size_t)row * 32 + l5];
        }
    }

    float z[4] = {0.f, 0.f, 0.f, 0.f};
    #pragma unroll
    for (int g = 0; g < 4; ++g) {
        float fa[16], fb[16], fc[16];
        decode16(r[g][0], fa);
        decode16(r[g][1], fb);
        decode16(r[g][2], fc);
        #pragma unroll
        for (int e = 0; e < 16; ++e) {
            float d = fa[e] - fb[e];
            float q = fa[e] - fc[e];
            z[g] += d * d - q * q;
        }
    }

    #pragma unroll
    for (int m = 1; m <= 16; m <<= 1) {
        #pragma unroll
        for (int g = 0; g < 4; ++g)
            z[g] += __shfl_xor(z[g], m, 64);
    }

    float sp = (softplus_stable(z[0]) + softplus_stable(z[1])) +
               (softplus_stable(z[2]) + softplus_stable(z[3]));
    sp += __shfl_xor(sp, 32, 64);

    __shared__ float wsum[4];
    if (lane == 0) wsum[wib] = sp;
    __syncthreads();
    if (threadIdx.x == 0)
        partials[blockIdx.x] = (wsum[0] + wsum[1]) + (wsum[2] + wsum[3]);
}

__global__ __launch_bounds__(1024) void reduce_kernel(
    const float* __restrict__ partials, float* __restrict__ out, int n)
{
    float s = 0.f;
    for (int idx = threadIdx.x; idx < n; idx += 1024)
        s += partials[idx];
    #pragma unroll
    for (int m = 1; m < 64; m <<= 1)
        s += __shfl_xor(s, m, 64);
    __shared__ float lds[1024 / 64];
    if ((threadIdx.x & 63) == 0) lds[threadIdx.x >> 6] = s;
    __syncthreads();
    if (threadIdx.x == 0) {
        float tot = 0.f;
        #pragma unroll
        for (int q = 0; q < 1024 / 64; ++q) tot += lds[q];
        out[0] = tot / (float)NTRIP;
    }
}

// ====================== fp32 fallback ======================
__global__ __launch_bounds__(256) void triplet_partial_f32(
    const float* __restrict__ x,
    const int*   __restrict__ trip,
    float*       __restrict__ partials)
{
    const int lane = threadIdx.x & 63;
    const int wib  = threadIdx.x >> 6;
    const int t    = blockIdx.x * 4 + wib;
    const int i = trip[3 * t + 0];
    const int j = trip[3 * t + 1];
    const int k = trip[3 * t + 2];
    const float4* pi = (const float4*)(x + (size_t)i * DIM) + lane * 2;
    const float4* pj = (const float4*)(x + (size_t)j * DIM) + lane * 2;
    const float4* pk = (const float4*)(x + (size_t)k * DIM) + lane * 2;
    float4 a0 = pi[0], a1 = pi[1];
    float4 b0 = pj[0], b1 = pj[1];
    float4 c0 = pk[0], c1 = pk[1];
    float z = 0.f;
    {
        float d;
        d = a0.x-b0.x; z += d*d; d = a0.y-b0.y; z += d*d;
        d = a0.z-b0.z; z += d*d; d = a0.w-b0.w; z += d*d;
        d = a1.x-b1.x; z += d*d; d = a1.y-b1.y; z += d*d;
        d = a1.z-b1.z; z += d*d; d = a1.w-b1.w; z += d*d;
        d = a0.x-c0.x; z -= d*d; d = a0.y-c0.y; z -= d*d;
        d = a0.z-c0.z; z -= d*d; d = a0.w-c0.w; z -= d*d;
        d = a1.x-c1.x; z -= d*d; d = a1.y-c1.y; z -= d*d;
        d = a1.z-c1.z; z -= d*d; d = a1.w-c1.w; z -= d*d;
    }
    #pragma unroll
    for (int m = 1; m < 64; m <<= 1) z += __shfl_xor(z, m, 64);
    __shared__ float wsum[4];
    if (lane == 0) wsum[wib] = softplus_stable(z);
    __syncthreads();
    if (threadIdx.x == 0)
        partials[blockIdx.x] = (wsum[0] + wsum[1]) + (wsum[2] + wsum[3]);
}

extern "C" void kernel_launch(void* const* d_in, const int* in_sizes, int n_in,
                              void* d_out, int out_size, void* d_ws, size_t ws_size,
                              hipStream_t stream) {
    const float* x    = (const float*)d_in[0];
    const int*   trip = (const int*)d_in[1];
    float*       out  = (float*)d_out;

    if (ws_size >= NEED_NEW) {
        uint4*        xq_s    = (uint4*)d_ws;
        float*        zp      = (float*)((char*)d_ws + XQS_BYTES);
        float*        slots   = (float*)((char*)d_ws + XQS_BYTES + ZP_BYTES);
        unsigned int* counter = (unsigned int*)((char*)d_ws + XQS_BYTES
                                 + ZP_BYTES + NSLOT * SLOT_STRIDE * 4);
        convert_slice_kernel<<<(NROWS * NSLICE) / 256, 256, 0, stream>>>(
            (const float4*)x, xq_s, slots, counter);
        slice_gather_kernel<<<NSLICE * GGRP, BT, 0, stream>>>(xq_s, trip, zp);
        combine_kernel<<<NSLOT, 256, 0, stream>>>(zp, slots, counter, out);
    } else if (ws_size >= NEED_R7) {
        uint4* xq       = (uint4*)d_ws;
        float* partials = (float*)((char*)d_ws + XQ_BYTES);
        convert8_row_kernel<<<(NROWS * DIM / 16) / 256, 256, 0, stream>>>(
            (const float4*)x, xq);
        gather8_kernel<<<R7_NBLK, 256, 0, stream>>>(xq, trip, partials);
        reduce_kernel<<<1, 1024, 0, stream>>>(partials, out, R7_NBLK);
    } else {
        float* partials = (float*)d_ws;
        triplet_partial_f32<<<NTRIP / 4, 256, 0, stream>>>(x, trip, partials);
        reduce_kernel<<<1, 1024, 0, stream>>>(partials, out, NTRIP / 4);
    }
}

// Round 12
// 27.341 us; speedup vs baseline: 2.2349x; 1.0047x over previous
//
#include <hip/hip_runtime.h>

// TripletLoss: N=8192, D=512, T=65536
//   loss = mean_t softplus(||x_i - x_j||^2 - ||x_i - x_k||^2)
//
// Round 12: r11 + full 2-stage software pipeline in kernel B:
//   indices prefetched 2 iterations ahead, LDS row-reads prefetched 1
//   iteration ahead (compute it | ds_read it+1 | index-load it+2).
//   Fully unrolled NIT=8, named-register rotation (no scratch arrays).
//   VGPR cost is free: occupancy is LDS-capped (128 KiB -> 1 block/CU).
//   A: fp32 -> fp8 e4m3 slice-major (16B/row/slice); zero slots+counter.
//   B: 256 blocks (32 slices x 8 groups), stage 128 KiB slice in LDS,
//      1 triplet/thread/iter, 3 random ds_read_b128, zp[s][t] coalesced.
//   C: 64 blocks combine slices + softplus + slot reduce (1 add/slot).
// Fallback tiers: ws < 12.01 MB -> r7 path (proven 30.2); < 4.07 MB -> fp32.

typedef float floatx2 __attribute__((ext_vector_type(2)));

#define NTRIP  65536
#define DIM    512
#define NROWS  8192
#define NSLICE 32                  // 16 B of fp8 per row per slice
#define SLICE_U4 NROWS             // uint4 per slice
#define GGRP   8                   // triplet groups
#define TRIP_PER_G (NTRIP / GGRP)  // 8192
#define BT     1024                // kernel B block size (16 waves)
#define NIT    (TRIP_PER_G / BT)   // 8
#define NSLOT  64
#define SLOT_STRIDE 16             // floats; 64 B apart

#define XQS_BYTES ((size_t)NSLICE * SLICE_U4 * 16)      // 4 MiB
#define ZP_BYTES  ((size_t)NSLICE * NTRIP * 4)          // 8 MiB
#define NEED_NEW  (XQS_BYTES + ZP_BYTES + NSLOT * SLOT_STRIDE * 4 + 64)
#define XQ_BYTES  ((size_t)NROWS * DIM)
#define R7_NBLK   2048
#define NEED_R7   (XQ_BYTES + (size_t)R7_NBLK * 4)

__device__ __forceinline__ float softplus_stable(float z) {
    return fmaxf(z, 0.f) + log1pf(expf(-fabsf(z)));
}

__device__ __forceinline__ unsigned int enc4(float a, float b, float c, float d) {
    unsigned int w = __builtin_amdgcn_cvt_pk_fp8_f32(a, b, 0, false);
    w = __builtin_amdgcn_cvt_pk_fp8_f32(c, d, w, true);
    return w;
}

__device__ __forceinline__ void decode4(unsigned int w, float* f) {
    floatx2 p0 = __builtin_amdgcn_cvt_pk_f32_fp8(w, false);
    floatx2 p1 = __builtin_amdgcn_cvt_pk_f32_fp8(w, true);
    f[0] = p0.x; f[1] = p0.y; f[2] = p1.x; f[3] = p1.y;
}

__device__ __forceinline__ void decode16(uint4 v, float* f) {
    decode4(v.x, f);     decode4(v.y, f + 4);
    decode4(v.z, f + 8); decode4(v.w, f + 12);
}

// ====================== NEW PATH (LDS slice) ======================

__global__ __launch_bounds__(256) void convert_slice_kernel(
    const float4* __restrict__ x, uint4* __restrict__ xq_s,
    float* __restrict__ slots, unsigned int* __restrict__ counter)
{
    if (blockIdx.x == 0) {
        if (threadIdx.x < NSLOT) slots[threadIdx.x * SLOT_STRIDE] = 0.f;
        if (threadIdx.x == NSLOT) *counter = 0u;
    }
    const int idx = blockIdx.x * 256 + threadIdx.x;   // 0 .. 262143
    const int s   = idx >> 13;                        // slice
    const int r   = idx & (NROWS - 1);                // row
    const float4* src = x + (size_t)r * (DIM / 4) + s * 4;
    float4 a = src[0], b = src[1], c = src[2], d = src[3];
    uint4 o;
    o.x = enc4(a.x, a.y, a.z, a.w);
    o.y = enc4(b.x, b.y, b.z, b.w);
    o.z = enc4(c.x, c.y, c.z, c.w);
    o.w = enc4(d.x, d.y, d.z, d.w);
    xq_s[idx] = o;                                    // = s*8192 + r
}

__global__ __launch_bounds__(BT) void slice_gather_kernel(
    const uint4* __restrict__ xq_s,
    const int*   __restrict__ trip,
    float*       __restrict__ zp)
{
    __shared__ uint4 sl[SLICE_U4];                    // 128 KiB
    const int s   = blockIdx.x & (NSLICE - 1);
    const int g   = blockIdx.x >> 5;
    const int tid = threadIdx.x;

    // stage slice s (contiguous 128 KB), coalesced
    const uint4* src = xq_s + (size_t)s * SLICE_U4;
    #pragma unroll
    for (int q = 0; q < SLICE_U4 / BT; ++q)           // 8
        sl[tid + q * BT] = src[tid + q * BT];
    __syncthreads();

    float* zrow = zp + (size_t)s * NTRIP;
    const int tbase = g * TRIP_PER_G + tid;

    // 2-stage pipeline: indices 2-deep, LDS data 1-deep.
    // compute(it) uses da/db/dc loaded during it-1; ds_read(it+1) uses
    // ni/nj/nk loaded during it-1; trip(it+2) issued now.
    int ni = trip[3 * tbase + 0];
    int nj = trip[3 * tbase + 1];
    int nk = trip[3 * tbase + 2];
    int pi = trip[3 * (tbase + BT) + 0];
    int pj = trip[3 * (tbase + BT) + 1];
    int pk = trip[3 * (tbase + BT) + 2];
    uint4 da = sl[ni], db = sl[nj], dc = sl[nk];
    ni = pi; nj = pj; nk = pk;

    #pragma unroll
    for (int it = 0; it < NIT; ++it) {                // 8
        // issue index loads for it+2
        pi = 0; pj = 0; pk = 0;
        if (it + 2 < NIT) {
            const int tn = tbase + (it + 2) * BT;
            pi = trip[3 * tn + 0];
            pj = trip[3 * tn + 1];
            pk = trip[3 * tn + 2];
        }
        // issue LDS reads for it+1
        uint4 ea = {0, 0, 0, 0}, eb = {0, 0, 0, 0}, ec = {0, 0, 0, 0};
        if (it + 1 < NIT) { ea = sl[ni]; eb = sl[nj]; ec = sl[nk]; }
        // compute it on previously-fetched registers
        float fa[16], fb[16], fc[16];
        decode16(da, fa); decode16(db, fb); decode16(dc, fc);
        float zz = 0.f;
        #pragma unroll
        for (int e = 0; e < 16; ++e) {
            float d = fa[e] - fb[e];
            float q = fa[e] - fc[e];
            zz += d * d - q * q;
        }
        zrow[tbase + it * BT] = zz;                   // coalesced
        // rotate pipeline registers (unroll renames -> no copies)
        da = ea; db = eb; dc = ec;
        ni = pi; nj = pj; nk = pk;
    }
}

__global__ __launch_bounds__(256) void combine_kernel(
    const float* __restrict__ zp,
    float*       __restrict__ slots,
    unsigned int* __restrict__ counter,
    float*       __restrict__ out)
{
    const int tid = threadIdx.x;
    float sp = 0.f;
    #pragma unroll
    for (int u = 0; u < 4; ++u) {
        const int t = blockIdx.x * 1024 + u * 256 + tid;
        float z = 0.f;
        #pragma unroll
        for (int s = 0; s < NSLICE; ++s)
            z += zp[(size_t)s * NTRIP + t];
        sp += softplus_stable(z);
    }
    #pragma unroll
    for (int m = 1; m < 64; m <<= 1)
        sp += __shfl_xor(sp, m, 64);

    __shared__ float ws[256 / 64];
    if ((tid & 63) == 0) ws[tid >> 6] = sp;
    __syncthreads();

    __shared__ bool amlast;
    if (tid == 0) {
        float bs = (ws[0] + ws[1]) + (ws[2] + ws[3]);
        atomicAdd(&slots[blockIdx.x * SLOT_STRIDE], bs);  // 1 add per slot
        unsigned int prev = __hip_atomic_fetch_add(
            counter, 1u, __ATOMIC_ACQ_REL, __HIP_MEMORY_SCOPE_AGENT);
        amlast = (prev == 63);
    }
    __syncthreads();

    if (amlast && tid < NSLOT) {
        float v = __hip_atomic_load(&slots[tid * SLOT_STRIDE],
                                    __ATOMIC_RELAXED, __HIP_MEMORY_SCOPE_AGENT);
        #pragma unroll
        for (int m = 1; m < NSLOT; m <<= 1)
            v += __shfl_xor(v, m, 64);
        if (tid == 0) out[0] = v / (float)NTRIP;
    }
}

// ====================== r7 PATH (proven 30.2 us) ======================

__global__ __launch_bounds__(256) void convert8_row_kernel(
    const float4* __restrict__ x, uint4* __restrict__ xq)
{
    const int idx = blockIdx.x * 256 + threadIdx.x;
    float4 a = x[(size_t)idx * 4 + 0];
    float4 b = x[(size_t)idx * 4 + 1];
    float4 c = x[(size_t)idx * 4 + 2];
    float4 d = x[(size_t)idx * 4 + 3];
    uint4 o;
    o.x = enc4(a.x, a.y, a.z, a.w);
    o.y = enc4(b.x, b.y, b.z, b.w);
    o.z = enc4(c.x, c.y, c.z, c.w);
    o.w = enc4(d.x, d.y, d.z, d.w);
    xq[idx] = o;
}

__global__ __launch_bounds__(256, 4) void gather8_kernel(
    const uint4* __restrict__ xq,
    const int*   __restrict__ trip,
    float*       __restrict__ partials)
{
    const int lane = threadIdx.x & 63;
    const int half = lane >> 5;
    const int l5   = lane & 31;
    const int wib  = threadIdx.x >> 6;
    const int t0   = (blockIdx.x * 4 + wib) * 8;

    const int4* tp = (const int4*)(trip + 3 * t0);
    int4 w0 = tp[0], w1 = tp[1], w2 = tp[2];
    int4 w3 = tp[3], w4 = tp[4], w5 = tp[5];
    const int id[24] = { w0.x, w0.y, w0.z, w0.w, w1.x, w1.y, w1.z, w1.w,
                         w2.x, w2.y, w2.z, w2.w, w3.x, w3.y, w3.z, w3.w,
                         w4.x, w4.y, w4.z, w4.w, w5.x, w5.y, w5.z, w5.w };

    uint4 r[4][3];
    #pragma unroll
    for (int g = 0; g < 4; ++g) {
        #pragma unroll
        for (int m = 0; m < 3; ++m) {
            const int row = half ? id[3 * (2 * g + 1) + m]
                                 : id[3 * (2 * g) + m];
            r[g][m] = xq[(size_t)row * 32 + l5];
        }
    }

    float z[4] = {0.f, 0.f, 0.f, 0.f};
    #pragma unroll
    for (int g = 0; g < 4; ++g) {
        float fa[16], fb[16], fc[16];
        decode16(r[g][0], fa);
        decode16(r[g][1], fb);
        decode16(r[g][2], fc);
        #pragma unroll
        for (int e = 0; e < 16; ++e) {
            float d = fa[e] - fb[e];
            float q = fa[e] - fc[e];
            z[g] += d * d - q * q;
        }
    }

    #pragma unroll
    for (int m = 1; m <= 16; m <<= 1) {
        #pragma unroll
        for (int g = 0; g < 4; ++g)
            z[g] += __shfl_xor(z[g], m, 64);
    }

    float sp = (softplus_stable(z[0]) + softplus_stable(z[1])) +
               (softplus_stable(z[2]) + softplus_stable(z[3]));
    sp += __shfl_xor(sp, 32, 64);

    __shared__ float wsum[4];
    if (lane == 0) wsum[wib] = sp;
    __syncthreads();
    if (threadIdx.x == 0)
        partials[blockIdx.x] = (wsum[0] + wsum[1]) + (wsum[2] + wsum[3]);
}

__global__ __launch_bounds__(1024) void reduce_kernel(
    const float* __restrict__ partials, float* __restrict__ out, int n)
{
    float s = 0.f;
    for (int idx = threadIdx.x; idx < n; idx += 1024)
        s += partials[idx];
    #pragma unroll
    for (int m = 1; m < 64; m <<= 1)
        s += __shfl_xor(s, m, 64);
    __shared__ float lds[1024 / 64];
    if ((threadIdx.x & 63) == 0) lds[threadIdx.x >> 6] = s;
    __syncthreads();
    if (threadIdx.x == 0) {
        float tot = 0.f;
        #pragma unroll
        for (int q = 0; q < 1024 / 64; ++q) tot += lds[q];
        out[0] = tot / (float)NTRIP;
    }
}

// ====================== fp32 fallback ======================
__global__ __launch_bounds__(256) void triplet_partial_f32(
    const float* __restrict__ x,
    const int*   __restrict__ trip,
    float*       __restrict__ partials)
{
    const int lane = threadIdx.x & 63;
    const int wib  = threadIdx.x >> 6;
    const int t    = blockIdx.x * 4 + wib;
    const int i = trip[3 * t + 0];
    const int j = trip[3 * t + 1];
    const int k = trip[3 * t + 2];
    const float4* pi = (const float4*)(x + (size_t)i * DIM) + lane * 2;
    const float4* pj = (const float4*)(x + (size_t)j * DIM) + lane * 2;
    const float4* pk = (const float4*)(x + (size_t)k * DIM) + lane * 2;
    float4 a0 = pi[0], a1 = pi[1];
    float4 b0 = pj[0], b1 = pj[1];
    float4 c0 = pk[0], c1 = pk[1];
    float z = 0.f;
    {
        float d;
        d = a0.x-b0.x; z += d*d; d = a0.y-b0.y; z += d*d;
        d = a0.z-b0.z; z += d*d; d = a0.w-b0.w; z += d*d;
        d = a1.x-b1.x; z += d*d; d = a1.y-b1.y; z += d*d;
        d = a1.z-b1.z; z += d*d; d = a1.w-b1.w; z += d*d;
        d = a0.x-c0.x; z -= d*d; d = a0.y-c0.y; z -= d*d;
        d = a0.z-c0.z; z -= d*d; d = a0.w-c0.w; z -= d*d;
        d = a1.x-c1.x; z -= d*d; d = a1.y-c1.y; z -= d*d;
        d = a1.z-c1.z; z -= d*d; d = a1.w-c1.w; z -= d*d;
    }
    #pragma unroll
    for (int m = 1; m < 64; m <<= 1) z += __shfl_xor(z, m, 64);
    __shared__ float wsum[4];
    if (lane == 0) wsum[wib] = softplus_stable(z);
    __syncthreads();
    if (threadIdx.x == 0)
        partials[blockIdx.x] = (wsum[0] + wsum[1]) + (wsum[2] + wsum[3]);
}

extern "C" void kernel_launch(void* const* d_in, const int* in_sizes, int n_in,
                              void* d_out, int out_size, void* d_ws, size_t ws_size,
                              hipStream_t stream) {
    const float* x    = (const float*)d_in[0];
    const int*   trip = (const int*)d_in[1];
    float*       out  = (float*)d_out;

    if (ws_size >= NEED_NEW) {
        uint4*        xq_s    = (uint4*)d_ws;
        float*        zp      = (float*)((char*)d_ws + XQS_BYTES);
        float*        slots   = (float*)((char*)d_ws + XQS_BYTES + ZP_BYTES);
        unsigned int* counter = (unsigned int*)((char*)d_ws + XQS_BYTES
                                 + ZP_BYTES + NSLOT * SLOT_STRIDE * 4);
        convert_slice_kernel<<<(NROWS * NSLICE) / 256, 256, 0, stream>>>(
            (const float4*)x, xq_s, slots, counter);
        slice_gather_kernel<<<NSLICE * GGRP, BT, 0, stream>>>(xq_s, trip, zp);
        combine_kernel<<<NSLOT, 256, 0, stream>>>(zp, slots, counter, out);
    } else if (ws_size >= NEED_R7) {
        uint4* xq       = (uint4*)d_ws;
        float* partials = (float*)((char*)d_ws + XQ_BYTES);
        convert8_row_kernel<<<(NROWS * DIM / 16) / 256, 256, 0, stream>>>(
            (const float4*)x, xq);
        gather8_kernel<<<R7_NBLK, 256, 0, stream>>>(xq, trip, partials);
        reduce_kernel<<<1, 1024, 0, stream>>>(partials, out, R7_NBLK);
    } else {
        float* partials = (float*)d_ws;
        triplet_partial_f32<<<NTRIP / 4, 256, 0, stream>>>(x, trip, partials);
        reduce_kernel<<<1, 1024, 0, stream>>>(partials, out, NTRIP / 4);
    }
}

// Round 13
// 24.994 us; speedup vs baseline: 2.4447x; 1.0939x over previous
//
#include <hip/hip_runtime.h>
#include <hip/hip_fp16.h>

// TripletLoss: N=8192, D=512, T=65536
//   loss = mean_t softplus(||x_i - x_j||^2 - ||x_i - x_k||^2)
//
// Round 13: DIAGNOSTIC round. Kernel B's cost has been invisible (poison
// fills ~40us dominate rocprof top-5). B's main loop now repeats
// DIAG_REPEAT=4x with an opaque salt (asm) preventing CSE -> B's dispatch
// ~4x loop cost, ranks in top-5 WITH counters. Output unchanged
// (idempotent rewrites). Also ships two real micro-opts that the
// diagnosis applies to:
//   - packed floatx2 compute (target v_pk_fma_f32): ~3.5 VALU/elem vs 5.5
//   - zp stored fp16: B-write + C-read traffic halved (16 -> 8 MB)
// Next round: DIAG_REPEAT -> 1 and act on B's counters.

typedef float floatx2 __attribute__((ext_vector_type(2)));

#define NTRIP  65536
#define DIM    512
#define NROWS  8192
#define NSLICE 32                  // 16 B of fp8 per row per slice
#define SLICE_U4 NROWS             // uint4 per slice
#define GGRP   8                   // triplet groups
#define TRIP_PER_G (NTRIP / GGRP)  // 8192
#define BT     1024                // kernel B block size (16 waves)
#define NIT    (TRIP_PER_G / BT)   // 8
#define NSLOT  64
#define SLOT_STRIDE 16             // floats; 64 B apart
#define DIAG_REPEAT 4              // diagnostic loop multiplier

#define XQS_BYTES ((size_t)NSLICE * SLICE_U4 * 16)      // 4 MiB
#define ZP_BYTES  ((size_t)NSLICE * NTRIP * 2)          // 4 MiB (fp16)
#define NEED_NEW  (XQS_BYTES + ZP_BYTES + NSLOT * SLOT_STRIDE * 4 + 64)
#define XQ_BYTES  ((size_t)NROWS * DIM)
#define R7_NBLK   2048
#define NEED_R7   (XQ_BYTES + (size_t)R7_NBLK * 4)

__device__ __forceinline__ float softplus_stable(float z) {
    return fmaxf(z, 0.f) + log1pf(expf(-fabsf(z)));
}

__device__ __forceinline__ unsigned int enc4(float a, float b, float c, float d) {
    unsigned int w = __builtin_amdgcn_cvt_pk_fp8_f32(a, b, 0, false);
    w = __builtin_amdgcn_cvt_pk_fp8_f32(c, d, w, true);
    return w;
}

__device__ __forceinline__ void decode16v(uint4 v, floatx2* f) {
    f[0] = __builtin_amdgcn_cvt_pk_f32_fp8(v.x, false);
    f[1] = __builtin_amdgcn_cvt_pk_f32_fp8(v.x, true);
    f[2] = __builtin_amdgcn_cvt_pk_f32_fp8(v.y, false);
    f[3] = __builtin_amdgcn_cvt_pk_f32_fp8(v.y, true);
    f[4] = __builtin_amdgcn_cvt_pk_f32_fp8(v.z, false);
    f[5] = __builtin_amdgcn_cvt_pk_f32_fp8(v.z, true);
    f[6] = __builtin_amdgcn_cvt_pk_f32_fp8(v.w, false);
    f[7] = __builtin_amdgcn_cvt_pk_f32_fp8(v.w, true);
}

__device__ __forceinline__ void decode4(unsigned int w, float* f) {
    floatx2 p0 = __builtin_amdgcn_cvt_pk_f32_fp8(w, false);
    floatx2 p1 = __builtin_amdgcn_cvt_pk_f32_fp8(w, true);
    f[0] = p0.x; f[1] = p0.y; f[2] = p1.x; f[3] = p1.y;
}

__device__ __forceinline__ void decode16(uint4 v, float* f) {
    decode4(v.x, f);     decode4(v.y, f + 4);
    decode4(v.z, f + 8); decode4(v.w, f + 12);
}

// ====================== NEW PATH (LDS slice) ======================

__global__ __launch_bounds__(256) void convert_slice_kernel(
    const float4* __restrict__ x, uint4* __restrict__ xq_s,
    float* __restrict__ slots, unsigned int* __restrict__ counter)
{
    if (blockIdx.x == 0) {
        if (threadIdx.x < NSLOT) slots[threadIdx.x * SLOT_STRIDE] = 0.f;
        if (threadIdx.x == NSLOT) *counter = 0u;
    }
    const int idx = blockIdx.x * 256 + threadIdx.x;   // 0 .. 262143
    const int s   = idx >> 13;                        // slice
    const int r   = idx & (NROWS - 1);                // row
    const float4* src = x + (size_t)r * (DIM / 4) + s * 4;
    float4 a = src[0], b = src[1], c = src[2], d = src[3];
    uint4 o;
    o.x = enc4(a.x, a.y, a.z, a.w);
    o.y = enc4(b.x, b.y, b.z, b.w);
    o.z = enc4(c.x, c.y, c.z, c.w);
    o.w = enc4(d.x, d.y, d.z, d.w);
    xq_s[idx] = o;                                    // = s*8192 + r
}

__global__ __launch_bounds__(BT) void slice_gather_kernel(
    const uint4* __restrict__ xq_s,
    const int*   __restrict__ trip,
    __half*      __restrict__ zph)
{
    __shared__ uint4 sl[SLICE_U4];                    // 128 KiB
    const int s   = blockIdx.x & (NSLICE - 1);
    const int g   = blockIdx.x >> 5;
    const int tid = threadIdx.x;

    // stage slice s (contiguous 128 KB), coalesced
    const uint4* src = xq_s + (size_t)s * SLICE_U4;
    #pragma unroll
    for (int q = 0; q < SLICE_U4 / BT; ++q)           // 8
        sl[tid + q * BT] = src[tid + q * BT];
    __syncthreads();

    __half* zrow = zph + (size_t)s * NTRIP;
    const int tbase = g * TRIP_PER_G + tid;

    // DIAGNOSTIC: opaque zero -> repeated passes can't be CSE'd away.
    int salt;
    asm volatile("v_mov_b32 %0, 0" : "=v"(salt));

    for (int rep = 0; rep < DIAG_REPEAT; ++rep) {
        // 2-stage pipeline: indices 2-deep, LDS data 1-deep.
        int ni = trip[3 * tbase + 0];
        int nj = trip[3 * tbase + 1];
        int nk = trip[3 * tbase + 2];
        int pi = trip[3 * (tbase + BT) + 0];
        int pj = trip[3 * (tbase + BT) + 1];
        int pk = trip[3 * (tbase + BT) + 2];
        uint4 da = sl[ni + salt], db = sl[nj + salt], dc = sl[nk + salt];
        ni = pi; nj = pj; nk = pk;

        #pragma unroll
        for (int it = 0; it < NIT; ++it) {            // 8
            pi = 0; pj = 0; pk = 0;
            if (it + 2 < NIT) {
                const int tn = tbase + (it + 2) * BT;
                pi = trip[3 * tn + 0];
                pj = trip[3 * tn + 1];
                pk = trip[3 * tn + 2];
            }
            uint4 ea = {0, 0, 0, 0}, eb = {0, 0, 0, 0}, ec = {0, 0, 0, 0};
            if (it + 1 < NIT) {
                ea = sl[ni + salt]; eb = sl[nj + salt]; ec = sl[nk + salt];
            }
            // packed compute on previously-fetched registers
            floatx2 fa[8], fb[8], fc[8];
            decode16v(da, fa); decode16v(db, fb); decode16v(dc, fc);
            floatx2 acc = {0.f, 0.f};
            #pragma unroll
            for (int e = 0; e < 8; ++e) {
                floatx2 d = fa[e] - fb[e];
                floatx2 q = fa[e] - fc[e];
                acc = acc + d * d;                    // v_pk_fma_f32
                acc = acc - q * q;                    // v_pk_fma_f32 (neg)
            }
            zrow[tbase + it * BT] = __float2half(acc[0] + acc[1]);
            da = ea; db = eb; dc = ec;
            ni = pi; nj = pj; nk = pk;
        }
    }
}

__global__ __launch_bounds__(256) void combine_kernel(
    const __half* __restrict__ zph,
    float*        __restrict__ slots,
    unsigned int* __restrict__ counter,
    float*        __restrict__ out)
{
    const int tid = threadIdx.x;
    float sp = 0.f;
    #pragma unroll
    for (int u = 0; u < 4; ++u) {
        const int t = blockIdx.x * 1024 + u * 256 + tid;
        float z = 0.f;
        #pragma unroll
        for (int s = 0; s < NSLICE; ++s)
            z += __half2float(zph[(size_t)s * NTRIP + t]);
        sp += softplus_stable(z);
    }
    #pragma unroll
    for (int m = 1; m < 64; m <<= 1)
        sp += __shfl_xor(sp, m, 64);

    __shared__ float ws[256 / 64];
    if ((tid & 63) == 0) ws[tid >> 6] = sp;
    __syncthreads();

    __shared__ bool amlast;
    if (tid == 0) {
        float bs = (ws[0] + ws[1]) + (ws[2] + ws[3]);
        atomicAdd(&slots[blockIdx.x * SLOT_STRIDE], bs);  // 1 add per slot
        unsigned int prev = __hip_atomic_fetch_add(
            counter, 1u, __ATOMIC_ACQ_REL, __HIP_MEMORY_SCOPE_AGENT);
        amlast = (prev == 63);
    }
    __syncthreads();

    if (amlast && tid < NSLOT) {
        float v = __hip_atomic_load(&slots[tid * SLOT_STRIDE],
                                    __ATOMIC_RELAXED, __HIP_MEMORY_SCOPE_AGENT);
        #pragma unroll
        for (int m = 1; m < NSLOT; m <<= 1)
            v += __shfl_xor(v, m, 64);
        if (tid == 0) out[0] = v / (float)NTRIP;
    }
}

// ====================== r7 PATH (proven 30.2 us) ======================

__global__ __launch_bounds__(256) void convert8_row_kernel(
    const float4* __restrict__ x, uint4* __restrict__ xq)
{
    const int idx = blockIdx.x * 256 + threadIdx.x;
    float4 a = x[(size_t)idx * 4 + 0];
    float4 b = x[(size_t)idx * 4 + 1];
    float4 c = x[(size_t)idx * 4 + 2];
    float4 d = x[(size_t)idx * 4 + 3];
    uint4 o;
    o.x = enc4(a.x, a.y, a.z, a.w);
    o.y = enc4(b.x, b.y, b.z, b.w);
    o.z = enc4(c.x, c.y, c.z, c.w);
    o.w = enc4(d.x, d.y, d.z, d.w);
    xq[idx] = o;
}

__global__ __launch_bounds__(256, 4) void gather8_kernel(
    const uint4* __restrict__ xq,
    const int*   __restrict__ trip,
    float*       __restrict__ partials)
{
    const int lane = threadIdx.x & 63;
    const int half = lane >> 5;
    const int l5   = lane & 31;
    const int wib  = threadIdx.x >> 6;
    const int t0   = (blockIdx.x * 4 + wib) * 8;

    const int4* tp = (const int4*)(trip + 3 * t0);
    int4 w0 = tp[0], w1 = tp[1], w2 = tp[2];
    int4 w3 = tp[3], w4 = tp[4], w5 = tp[5];
    const int id[24] = { w0.x, w0.y, w0.z, w0.w, w1.x, w1.y, w1.z, w1.w,
                         w2.x, w2.y, w2.z, w2.w, w3.x, w3.y, w3.z, w3.w,
                         w4.x, w4.y, w4.z, w4.w, w5.x, w5.y, w5.z, w5.w };

    uint4 r[4][3];
    #pragma unroll
    for (int g = 0; g < 4; ++g) {
        #pragma unroll
        for (int m = 0; m < 3; ++m) {
            const int row = half ? id[3 * (2 * g + 1) + m]
                                 : id[3 * (2 * g) + m];
            r[g][m] = xq[(size_t)row * 32 + l5];
        }
    }

    float z[4] = {0.f, 0.f, 0.f, 0.f};
    #pragma unroll
    for (int g = 0; g < 4; ++g) {
        float fa[16], fb[16], fc[16];
        decode16(r[g][0], fa);
        decode16(r[g][1], fb);
        decode16(r[g][2], fc);
        #pragma unroll
        for (int e = 0; e < 16; ++e) {
            float d = fa[e] - fb[e];
            float q = fa[e] - fc[e];
            z[g] += d * d - q * q;
        }
    }

    #pragma unroll
    for (int m = 1; m <= 16; m <<= 1) {
        #pragma unroll
        for (int g = 0; g < 4; ++g)
            z[g] += __shfl_xor(z[g], m, 64);
    }

    float sp = (softplus_stable(z[0]) + softplus_stable(z[1])) +
               (softplus_stable(z[2]) + softplus_stable(z[3]));
    sp += __shfl_xor(sp, 32, 64);

    __shared__ float wsum[4];
    if (lane == 0) wsum[wib] = sp;
    __syncthreads();
    if (threadIdx.x == 0)
        partials[blockIdx.x] = (wsum[0] + wsum[1]) + (wsum[2] + wsum[3]);
}

__global__ __launch_bounds__(1024) void reduce_kernel(
    const float* __restrict__ partials, float* __restrict__ out, int n)
{
    float s = 0.f;
    for (int idx = threadIdx.x; idx < n; idx += 1024)
        s += partials[idx];
    #pragma unroll
    for (int m = 1; m < 64; m <<= 1)
        s += __shfl_xor(s, m, 64);
    __shared__ float lds[1024 / 64];
    if ((threadIdx.x & 63) == 0) lds[threadIdx.x >> 6] = s;
    __syncthreads();
    if (threadIdx.x == 0) {
        float tot = 0.f;
        #pragma unroll
        for (int q = 0; q < 1024 / 64; ++q) tot += lds[q];
        out[0] = tot / (float)NTRIP;
    }
}

// ====================== fp32 fallback ======================
__global__ __launch_bounds__(256) void triplet_partial_f32(
    const float* __restrict__ x,
    const int*   __restrict__ trip,
    float*       __restrict__ partials)
{
    const int lane = threadIdx.x & 63;
    const int wib  = threadIdx.x >> 6;
    const int t    = blockIdx.x * 4 + wib;
    const int i = trip[3 * t + 0];
    const int j = trip[3 * t + 1];
    const int k = trip[3 * t + 2];
    const float4* pi = (const float4*)(x + (size_t)i * DIM) + lane * 2;
    const float4* pj = (const float4*)(x + (size_t)j * DIM) + lane * 2;
    const float4* pk = (const float4*)(x + (size_t)k * DIM) + lane * 2;
    float4 a0 = pi[0], a1 = pi[1];
    float4 b0 = pj[0], b1 = pj[1];
    float4 c0 = pk[0], c1 = pk[1];
    float z = 0.f;
    {
        float d;
        d = a0.x-b0.x; z += d*d; d = a0.y-b0.y; z += d*d;
        d = a0.z-b0.z; z += d*d; d = a0.w-b0.w; z += d*d;
        d = a1.x-b1.x; z += d*d; d = a1.y-b1.y; z += d*d;
        d = a1.z-b1.z; z += d*d; d = a1.w-b1.w; z += d*d;
        d = a0.x-c0.x; z -= d*d; d = a0.y-c0.y; z -= d*d;
        d = a0.z-c0.z; z -= d*d; d = a0.w-c0.w; z -= d*d;
        d = a1.x-c1.x; z -= d*d; d = a1.y-c1.y; z -= d*d;
        d = a1.z-c1.z; z -= d*d; d = a1.w-c1.w; z -= d*d;
    }
    #pragma unroll
    for (int m = 1; m < 64; m <<= 1) z += __shfl_xor(z, m, 64);
    __shared__ float wsum[4];
    if (lane == 0) wsum[wib] = softplus_stable(z);
    __syncthreads();
    if (threadIdx.x == 0)
        partials[blockIdx.x] = (wsum[0] + wsum[1]) + (wsum[2] + wsum[3]);
}

extern "C" void kernel_launch(void* const* d_in, const int* in_sizes, int n_in,
                              void* d_out, int out_size, void* d_ws, size_t ws_size,
                              hipStream_t stream) {
    const float* x    = (const float*)d_in[0];
    const int*   trip = (const int*)d_in[1];
    float*       out  = (float*)d_out;

    if (ws_size >= NEED_NEW) {
        uint4*        xq_s    = (uint4*)d_ws;
        __half*       zph     = (__half*)((char*)d_ws + XQS_BYTES);
        float*        slots   = (float*)((char*)d_ws + XQS_BYTES + ZP_BYTES);
        unsigned int* counter = (unsigned int*)((char*)d_ws + XQS_BYTES
                                 + ZP_BYTES + NSLOT * SLOT_STRIDE * 4);
        convert_slice_kernel<<<(NROWS * NSLICE) / 256, 256, 0, stream>>>(
            (const float4*)x, xq_s, slots, counter);
        slice_gather_kernel<<<NSLICE * GGRP, BT, 0, stream>>>(xq_s, trip, zph);
        combine_kernel<<<NSLOT, 256, 0, stream>>>(zph, slots, counter, out);
    } else if (ws_size >= NEED_R7) {
        uint4* xq       = (uint4*)d_ws;
        float* partials = (float*)((char*)d_ws + XQ_BYTES);
        convert8_row_kernel<<<(NROWS * DIM / 16) / 256, 256, 0, stream>>>(
            (const float4*)x, xq);
        gather8_kernel<<<R7_NBLK, 256, 0, stream>>>(xq, trip, partials);
        reduce_kernel<<<1, 1024, 0, stream>>>(partials, out, R7_NBLK);
    } else {
        float* partials = (float*)d_ws;
        triplet_partial_f32<<<NTRIP / 4, 256, 0, stream>>>(x, trip, partials);
        reduce_kernel<<<1, 1024, 0, stream>>>(partials, out, NTRIP / 4);
    }
}